// Round 15
// baseline (586.017 us; speedup 1.0000x reference)
//
#include <hip/hip_runtime.h>
#include <math.h>

typedef __attribute__((ext_vector_type(8))) short s16x8;   // 8 bf16 (4 VGPRs)
typedef __attribute__((ext_vector_type(4))) float f32x4;   // MFMA accumulator

__device__ __forceinline__ short f2bf(float x){
  unsigned u = __float_as_uint(x);
  u += 0x7fff + ((u >> 16) & 1);        // round-to-nearest-even
  return (short)(u >> 16);
}
__device__ __forceinline__ float bf2f(short s){
  return __uint_as_float(((unsigned)(unsigned short)s) << 16);
}

// ---------------- fp32 -> bf16 convert (n % 4 == 0) ----------------
__global__ void k_cvt(const float* __restrict__ in, short* __restrict__ outb, int n4){
  int i = blockIdx.x*blockDim.x + threadIdx.x;
  if (i >= n4) return;
  float4 v = ((const float4*)in)[i];
  short4 u; u.x = f2bf(v.x); u.y = f2bf(v.y); u.z = f2bf(v.z); u.w = f2bf(v.w);
  ((short4*)outb)[i] = u;
}

// ---------------- weight transpose+convert: Wt[n][k] (bf16) from W[k][n] (fp32) ----------------
__global__ void k_wt(const float* W, short* Wt, int K){
  int idx = blockIdx.x*blockDim.x + threadIdx.x;
  if (idx >= 256*K) return;
  int n = idx / K, k = idx - n*K;
  Wt[idx] = f2bf(W[(size_t)k*256 + n]);
}

// 3 cvec reductions in one launch: block 0 -> NH=16 @cvec[0], 1 -> NH=16 @cvec[16], 2 -> NH=1 @cvec[32]
__global__ void k_cvec3(const float* __restrict__ Wtp0, const float* __restrict__ a0,
                        const float* __restrict__ Wtp1, const float* __restrict__ a1,
                        const float* __restrict__ Wtp2, const float* __restrict__ a2,
                        float* __restrict__ cvec){
  __shared__ float buf[256];
  int c = blockIdx.x, t = threadIdx.x;
  const float* Wtp = (c == 0) ? Wtp0 : ((c == 1) ? Wtp1 : Wtp2);
  const float* atp = (c == 0) ? a0 : ((c == 1) ? a1 : a2);
  int NH = (c == 2) ? 1 : 16;
  buf[t] = Wtp[t] * atp[t];
  __syncthreads();
  int F = 256 / NH;
  if (t < NH){
    float s = 0.f;
    for (int f = 0; f < F; f++) s += buf[t*F + f];
    cvec[c*16 + t] = s;
  }
}

// ---------------- CSR build (sort edges by target) ----------------
__global__ void k_zero(int* p, int n){
  int i = blockIdx.x*blockDim.x + threadIdx.x;
  if (i < n) p[i] = 0;
}
__global__ void k_hist(const int* tgt, int* counts, int E){
  int i = blockIdx.x*blockDim.x + threadIdx.x;
  if (i < E) atomicAdd(&counts[tgt[i]], 1);
}
__global__ void k_scan1(const int* counts, int* row_excl, int* partials, int N){
  __shared__ int buf[1024];
  int t = threadIdx.x; int i = blockIdx.x*1024 + t;
  int v = (i < N) ? counts[i] : 0;
  buf[t] = v; __syncthreads();
  for (int o = 1; o < 1024; o <<= 1){
    int x = (t >= o) ? buf[t-o] : 0;
    __syncthreads();
    buf[t] += x;
    __syncthreads();
  }
  if (i < N) row_excl[i] = buf[t] - v;
  if (t == 1023) partials[blockIdx.x] = buf[1023];
}
__global__ void k_scan2(int* partials, int NB){
  if (threadIdx.x == 0 && blockIdx.x == 0){
    int s = 0;
    for (int b = 0; b < NB; b++){ int v = partials[b]; partials[b] = s; s += v; }
  }
}
__global__ void k_scan3(int* row_start, const int* partials, int* cursor, int N, int E){
  int i = blockIdx.x*blockDim.x + threadIdx.x;
  if (i < N){
    int v = row_start[i] + partials[i >> 10];
    row_start[i] = v; cursor[i] = v;
  }
  if (i == 0) row_start[N] = E;
}
// packed edge record: (src, tp as float bits) — one 8 B store per edge
__global__ void k_scatter(const int* src, const int* tgt, const float* eprob,
                          int* cursor, int2* es, int E){
  int i = blockIdx.x*blockDim.x + threadIdx.x;
  if (i >= E) return;
  int tg = tgt[i];
  int p = atomicAdd(&cursor[tg], 1);
  int2 e; e.x = src[i]; e.y = __float_as_int(eprob[i]);
  es[p] = e;
}

// ---------------- LDS-staged MFMA GEMM, dual-B fused ----------------
// DUAL=1: one block computes proj (B1 -> C1b, + fused NH=16 svec from fp32 accs)
//         AND skip (B2 -> C2b) for its 64-row tile; A staged once.
// DUAL=0: proj only (svec skipped when asrc==null).
template<int KC, int DUAL>   // KC: K/32 chunks (4 or 8)
__global__ __launch_bounds__(256)
void k_gemm_lds(const short* __restrict__ Ab,
                const short* __restrict__ B1t, const short* __restrict__ B2t,
                short* __restrict__ C1b, short* __restrict__ C2b,
                const float* __restrict__ asrc, const float* __restrict__ atgt,
                float* __restrict__ s_src, float* __restrict__ s_tgt, int M){
  const int K = KC*32;
  __shared__ short lA[64*32];                 // 4 KB
  __shared__ short lB[(DUAL+1)*256*32];       // 16/32 KB
  const int tid  = threadIdx.x;
  const int lane = tid & 63;
  const int wave = tid >> 6;
  const int m16  = lane & 15;
  const int q    = lane >> 4;
  const int swz  = (m16 >> 1) & 3;
  const int r0   = blockIdx.x * 64;

  int arow = r0 + (tid >> 2); if (arow >= M) arow = M - 1;
  const int akq = (tid & 3) ^ ((tid >> 3) & 3);
  int bn[4], bkq[4];
  #pragma unroll
  for (int j = 0; j < 4; j++){
    int sj = j*256 + tid;
    bn[j]  = sj >> 2;
    bkq[j] = (sj & 3) ^ ((sj >> 3) & 3);
  }

  f32x4 acc1[4][4], acc2[4][4];
  #pragma unroll
  for (int mi = 0; mi < 4; mi++)
    #pragma unroll
    for (int ni = 0; ni < 4; ni++){
      acc1[mi][ni] = {0.f,0.f,0.f,0.f};
      if (DUAL) acc2[mi][ni] = {0.f,0.f,0.f,0.f};
    }

  s16x8 ra = *(const s16x8*)(Ab + (size_t)arow*K + akq*8);
  s16x8 rb1[4], rb2[4];
  #pragma unroll
  for (int j = 0; j < 4; j++){
    rb1[j] = *(const s16x8*)(B1t + (size_t)bn[j]*K + bkq[j]*8);
    if (DUAL) rb2[j] = *(const s16x8*)(B2t + (size_t)bn[j]*K + bkq[j]*8);
  }

  for (int c = 0; c < KC; c++){
    __syncthreads();                     // previous chunk's reads complete
    *(s16x8*)(lA + tid*8) = ra;
    #pragma unroll
    for (int j = 0; j < 4; j++){
      *(s16x8*)(lB + (j*256 + tid)*8) = rb1[j];
      if (DUAL) *(s16x8*)(lB + (256*32) + (j*256 + tid)*8) = rb2[j];
    }
    __syncthreads();

    if (c + 1 < KC){                     // prefetch next chunk into regs
      int k0 = (c+1)*32;
      ra = *(const s16x8*)(Ab + (size_t)arow*K + k0 + akq*8);
      #pragma unroll
      for (int j = 0; j < 4; j++){
        rb1[j] = *(const s16x8*)(B1t + (size_t)bn[j]*K + k0 + bkq[j]*8);
        if (DUAL) rb2[j] = *(const s16x8*)(B2t + (size_t)bn[j]*K + k0 + bkq[j]*8);
      }
    }

    s16x8 Af[4], Bf[4];
    #pragma unroll
    for (int mi = 0; mi < 4; mi++){
      int slot = (mi*16 + m16)*4 + (q ^ swz);
      Af[mi] = *(const s16x8*)(lA + slot*8);
    }
    #pragma unroll
    for (int ni = 0; ni < 4; ni++){
      int slot = (wave*64 + ni*16 + m16)*4 + (q ^ swz);
      Bf[ni] = *(const s16x8*)(lB + slot*8);
    }
    #pragma unroll
    for (int mi = 0; mi < 4; mi++)
      #pragma unroll
      for (int ni = 0; ni < 4; ni++)
        acc1[mi][ni] = __builtin_amdgcn_mfma_f32_16x16x32_bf16(Bf[ni], Af[mi], acc1[mi][ni], 0, 0, 0);
    if (DUAL){
      #pragma unroll
      for (int ni = 0; ni < 4; ni++){
        int slot = (wave*64 + ni*16 + m16)*4 + (q ^ swz);
        Bf[ni] = *(const s16x8*)(lB + (256*32) + slot*8);
      }
      #pragma unroll
      for (int mi = 0; mi < 4; mi++)
        #pragma unroll
        for (int ni = 0; ni < 4; ni++)
          acc2[mi][ni] = __builtin_amdgcn_mfma_f32_16x16x32_bf16(Bf[ni], Af[mi], acc2[mi][ni], 0, 0, 0);
    }
  }

  #pragma unroll
  for (int mi = 0; mi < 4; mi++){
    int row = r0 + mi*16 + m16;
    bool ok = (row < M);
    #pragma unroll
    for (int ni = 0; ni < 4; ni++){
      size_t o = (size_t)row*256 + wave*64 + ni*16 + q*4;
      if (ok){
        short4 u; u.x = f2bf(acc1[mi][ni][0]); u.y = f2bf(acc1[mi][ni][1]);
        u.z = f2bf(acc1[mi][ni][2]); u.w = f2bf(acc1[mi][ni][3]);
        *(short4*)(C1b + o) = u;
        if (DUAL){
          short4 v; v.x = f2bf(acc2[mi][ni][0]); v.y = f2bf(acc2[mi][ni][1]);
          v.z = f2bf(acc2[mi][ni][2]); v.w = f2bf(acc2[mi][ni][3]);
          *(short4*)(C2b + o) = v;
        }
      }
      if (asrc){
        // fused svec: head hh = wave*4+ni; lane holds features q*4..q*4+3 of row
        int hh = wave*4 + ni;
        const float* as = asrc + hh*16 + q*4;
        const float* at = atgt + hh*16 + q*4;
        float pss = acc1[mi][ni][0]*as[0] + acc1[mi][ni][1]*as[1]
                  + acc1[mi][ni][2]*as[2] + acc1[mi][ni][3]*as[3];
        float pst = acc1[mi][ni][0]*at[0] + acc1[mi][ni][1]*at[1]
                  + acc1[mi][ni][2]*at[2] + acc1[mi][ni][3]*at[3];
        pss += __shfl_xor(pss, 16); pss += __shfl_xor(pss, 32);
        pst += __shfl_xor(pst, 16); pst += __shfl_xor(pst, 32);
        if (ok && q == 0){
          s_src[row*16 + hh] = pss;
          s_tgt[row*16 + hh] = pst;
        }
      }
    }
  }
}

// ---------------- NH=1 score projections from bf16 proj (wave per node) ----------------
__global__ void k_svec1(const short* __restrict__ Pb,
                        const float* __restrict__ a_src, const float* __restrict__ a_tgt,
                        float* __restrict__ s_src, float* __restrict__ s_tgt, int N){
  int lane = threadIdx.x & 63;
  int node = blockIdx.x*(blockDim.x >> 6) + (threadIdx.x >> 6);
  if (node >= N) return;
  short4 p = ((const short4*)(Pb + (size_t)node*256))[lane];
  const float* as = a_src + lane*4;
  const float* at = a_tgt + lane*4;
  float f0 = bf2f(p.x), f1 = bf2f(p.y), f2 = bf2f(p.z), f3 = bf2f(p.w);
  float ss = f0*as[0] + f1*as[1] + f2*as[2] + f3*as[3];
  float st = f0*at[0] + f1*at[1] + f2*at[2] + f3*at[3];
  for (int o = 32; o > 0; o >>= 1){ ss += __shfl_xor(ss, o); st += __shfl_xor(st, o); }
  if (lane == 0){ s_src[node] = ss; s_tgt[node] = st; }
}

// ---------------- single-pass fused attention (bf16 proj gather, no max-subtraction) ----------------
// NH=16: lane (h2=lane>>2, slot=lane&3); chunks of 4 edges; next-chunk edge record
// prefetched to overlap the gather latency. w = exp(e) directly (|e| small, shift-invariant).
template<int LN>
__global__ void k_attn16(const int* __restrict__ row_start, const int2* __restrict__ es,
                         const float* __restrict__ s_src, const float* __restrict__ s_tgt,
                         const float* __restrict__ cvec,
                         const short* __restrict__ projb, const short* __restrict__ skipb,
                         const float* __restrict__ bias,
                         const float* __restrict__ ln_g, const float* __restrict__ ln_b,
                         short* __restrict__ houtb, int N){
  const int lane = threadIdx.x & 63;
  const int node = blockIdx.x*(blockDim.x >> 6) + (threadIdx.x >> 6);
  if (node >= N) return;
  const int beg = row_start[node], end = row_start[node+1];

  const int h2    = lane >> 2;
  const int slot  = lane & 3;
  const int qbase = lane & 60;
  const float ch = cvec[h2];
  const float st = s_tgt[node*16 + h2];

  float d = 0.f;
  float acc0 = 0.f, acc1 = 0.f, acc2 = 0.f, acc3 = 0.f;

  int i0 = beg + slot;
  int2 ed = (beg < end) ? es[(i0 < end) ? i0 : (end - 1)] : make_int2(0,0);

  for (int cb = beg; cb < end; cb += 4){
    int sv = ed.x;
    float tp = __int_as_float(ed.y);
    bool valid = (cb + slot < end);
    float e = s_src[sv*16 + h2] + st + tp*ch;
    e = (e > 0.f) ? e : 0.2f*e;
    float w = valid ? __expf(e) : 0.f;
    // prefetch next chunk's edge record (independent of this chunk's gathers)
    if (cb + 4 < end){
      int inext = cb + 4 + slot;
      ed = es[(inext < end) ? inext : (end - 1)];
    }
    float qs = w + __shfl_xor(w, 1);
    qs = qs + __shfl_xor(qs, 2);
    d += qs;
    if (cb + 4 <= end){
      float w0 = __shfl(w, qbase+0), w1 = __shfl(w, qbase+1);
      float w2 = __shfl(w, qbase+2), w3 = __shfl(w, qbase+3);
      int   s0 = __shfl(sv, qbase+0), s1 = __shfl(sv, qbase+1);
      int   s2 = __shfl(sv, qbase+2), s3 = __shfl(sv, qbase+3);
      short4 p0 = ((const short4*)(projb + (size_t)s0*256))[lane];
      short4 p1 = ((const short4*)(projb + (size_t)s1*256))[lane];
      short4 p2 = ((const short4*)(projb + (size_t)s2*256))[lane];
      short4 p3 = ((const short4*)(projb + (size_t)s3*256))[lane];
      acc0 += w0*bf2f(p0.x) + w1*bf2f(p1.x) + w2*bf2f(p2.x) + w3*bf2f(p3.x);
      acc1 += w0*bf2f(p0.y) + w1*bf2f(p1.y) + w2*bf2f(p2.y) + w3*bf2f(p3.y);
      acc2 += w0*bf2f(p0.z) + w1*bf2f(p1.z) + w2*bf2f(p2.z) + w3*bf2f(p3.z);
      acc3 += w0*bf2f(p0.w) + w1*bf2f(p1.w) + w2*bf2f(p2.w) + w3*bf2f(p3.w);
    } else {
      int nval = end - cb;
      for (int j = 0; j < nval; j++){
        float wj = __shfl(w,  qbase + j);
        int   sj = __shfl(sv, qbase + j);
        short4 p = ((const short4*)(projb + (size_t)sj*256))[lane];
        acc0 += wj*bf2f(p.x); acc1 += wj*bf2f(p.y);
        acc2 += wj*bf2f(p.z); acc3 += wj*bf2f(p.w);
      }
    }
  }
  float inv = 1.f / (d + 1e-16f);

  short4 sk = ((const short4*)(skipb + (size_t)node*256))[lane];
  float acc[4];
  acc[0] = acc0*inv + bf2f(sk.x); acc[1] = acc1*inv + bf2f(sk.y);
  acc[2] = acc2*inv + bf2f(sk.z); acc[3] = acc3*inv + bf2f(sk.w);

  #pragma unroll
  for (int j = 0; j < 4; j++){
    float v = acc[j] + bias[lane*4 + j];
    acc[j] = (v > 0.f) ? v : (__expf(v) - 1.f);
  }
  if (LN){
    float s  = acc[0] + acc[1] + acc[2] + acc[3];
    float s2 = acc[0]*acc[0] + acc[1]*acc[1] + acc[2]*acc[2] + acc[3]*acc[3];
    for (int o = 32; o > 0; o >>= 1){ s += __shfl_xor(s, o); s2 += __shfl_xor(s2, o); }
    float mu  = s * (1.f/256.f);
    float var = s2 * (1.f/256.f) - mu*mu;
    float rs  = rsqrtf(var + 1e-5f);
    #pragma unroll
    for (int j = 0; j < 4; j++)
      acc[j] = (acc[j] - mu)*rs*ln_g[lane*4 + j] + ln_b[lane*4 + j];
  }
  short4 ub; ub.x = f2bf(acc[0]); ub.y = f2bf(acc[1]);
  ub.z = f2bf(acc[2]); ub.w = f2bf(acc[3]);
  ((short4*)(houtb + (size_t)node*256))[lane] = ub;
}

// NH=1 variant: 64-edge chunks score in parallel; aggregation unrolled 4-wide.
// bf16 identity skip, LN, bf16 out.
__global__ void k_attn1(const int* __restrict__ row_start, const int2* __restrict__ es,
                        const float* __restrict__ s_src, const float* __restrict__ s_tgt,
                        const float* __restrict__ cvec,
                        const short* __restrict__ projb, const short* __restrict__ skipb,
                        const float* __restrict__ bias,
                        const float* __restrict__ ln_g, const float* __restrict__ ln_b,
                        short* __restrict__ houtb, int N){
  const int lane = threadIdx.x & 63;
  const int node = blockIdx.x*(blockDim.x >> 6) + (threadIdx.x >> 6);
  if (node >= N) return;
  const int beg = row_start[node], end = row_start[node+1];

  const float c0 = cvec[0];
  const float st = s_tgt[node];
  float d = 0.f;
  float acc0 = 0.f, acc1 = 0.f, acc2 = 0.f, acc3 = 0.f;

  for (int cb = beg; cb < end; cb += 64){
    int i  = cb + lane;
    int2 ed = es[(i < end) ? i : (end - 1)];
    int sv = ed.x;
    float e = s_src[sv] + st + __int_as_float(ed.y)*c0;
    e = (e > 0.f) ? e : 0.2f*e;
    float w = (i < end) ? __expf(e) : 0.f;
    float qs = w;
    for (int o = 1; o <= 32; o <<= 1) qs += __shfl_xor(qs, o);
    d += qs;
    int nval = end - cb; if (nval > 64) nval = 64;
    int j = 0;
    for (; j + 4 <= nval; j += 4){
      float w0 = __shfl(w, j+0), w1 = __shfl(w, j+1);
      float w2 = __shfl(w, j+2), w3 = __shfl(w, j+3);
      int   s0 = __shfl(sv, j+0), s1 = __shfl(sv, j+1);
      int   s2 = __shfl(sv, j+2), s3 = __shfl(sv, j+3);
      short4 p0 = ((const short4*)(projb + (size_t)s0*256))[lane];
      short4 p1 = ((const short4*)(projb + (size_t)s1*256))[lane];
      short4 p2 = ((const short4*)(projb + (size_t)s2*256))[lane];
      short4 p3 = ((const short4*)(projb + (size_t)s3*256))[lane];
      acc0 += w0*bf2f(p0.x) + w1*bf2f(p1.x) + w2*bf2f(p2.x) + w3*bf2f(p3.x);
      acc1 += w0*bf2f(p0.y) + w1*bf2f(p1.y) + w2*bf2f(p2.y) + w3*bf2f(p3.y);
      acc2 += w0*bf2f(p0.z) + w1*bf2f(p1.z) + w2*bf2f(p2.z) + w3*bf2f(p3.z);
      acc3 += w0*bf2f(p0.w) + w1*bf2f(p1.w) + w2*bf2f(p2.w) + w3*bf2f(p3.w);
    }
    for (; j < nval; j++){
      float wj = __shfl(w,  j);
      int   sj = __shfl(sv, j);
      short4 p = ((const short4*)(projb + (size_t)sj*256))[lane];
      acc0 += wj*bf2f(p.x); acc1 += wj*bf2f(p.y);
      acc2 += wj*bf2f(p.z); acc3 += wj*bf2f(p.w);
    }
  }
  float inv = 1.f / (d + 1e-16f);

  short4 sk = ((const short4*)(skipb + (size_t)node*256))[lane];
  float acc[4];
  acc[0] = acc0*inv + bf2f(sk.x); acc[1] = acc1*inv + bf2f(sk.y);
  acc[2] = acc2*inv + bf2f(sk.z); acc[3] = acc3*inv + bf2f(sk.w);

  #pragma unroll
  for (int j = 0; j < 4; j++){
    float v = acc[j] + bias[lane*4 + j];
    acc[j] = (v > 0.f) ? v : (__expf(v) - 1.f);
  }
  float s  = acc[0] + acc[1] + acc[2] + acc[3];
  float s2 = acc[0]*acc[0] + acc[1]*acc[1] + acc[2]*acc[2] + acc[3]*acc[3];
  for (int o = 32; o > 0; o >>= 1){ s += __shfl_xor(s, o); s2 += __shfl_xor(s2, o); }
  float mu  = s * (1.f/256.f);
  float var = s2 * (1.f/256.f) - mu*mu;
  float rs  = rsqrtf(var + 1e-5f);
  #pragma unroll
  for (int j = 0; j < 4; j++)
    acc[j] = (acc[j] - mu)*rs*ln_g[lane*4 + j] + ln_b[lane*4 + j];
  short4 ub; ub.x = f2bf(acc[0]); ub.y = f2bf(acc[1]);
  ub.z = f2bf(acc[2]); ub.w = f2bf(acc[3]);
  ((short4*)(houtb + (size_t)node*256))[lane] = ub;
}

// ---------------- final gather (bf16 h -> fp32 out) ----------------
__global__ void k_gather(const short* hb, const int* x, float* out, int R){
  int r = blockIdx.x, t = threadIdx.x;
  if (r >= R) return;
  out[(size_t)r*256 + t] = bf2f(hb[(size_t)x[r]*256 + t]);
}

extern "C" void kernel_launch(void* const* d_in, const int* in_sizes, int n_in,
                              void* d_out, int out_size, void* d_ws, size_t ws_size,
                              hipStream_t stream){
  const int N = in_sizes[0] / 128;   // 50000
  const int E = in_sizes[1] / 2;     // 800000
  const int R = in_sizes[3];         // 8192

  const float* nf    = (const float*)d_in[0];
  const int*   ei    = (const int*)d_in[1];
  const float* eprob = (const float*)d_in[2];
  const int*   xidx  = (const int*)d_in[3];
  const float* W0     = (const float*)d_in[4];
  const float* a_src0 = (const float*)d_in[5];
  const float* a_tgt0 = (const float*)d_in[6];
  const float* Wtp0   = (const float*)d_in[7];
  const float* a_tp0  = (const float*)d_in[8];
  const float* Wskip0 = (const float*)d_in[9];
  const float* b0     = (const float*)d_in[10];
  const float* W1     = (const float*)d_in[11];
  const float* a_src1 = (const float*)d_in[12];
  const float* a_tgt1 = (const float*)d_in[13];
  const float* Wtp1   = (const float*)d_in[14];
  const float* a_tp1  = (const float*)d_in[15];
  const float* Wskip1 = (const float*)d_in[16];
  const float* b1     = (const float*)d_in[17];
  const float* ln1_g  = (const float*)d_in[18];
  const float* ln1_b  = (const float*)d_in[19];
  const float* W2     = (const float*)d_in[20];
  const float* a_src2 = (const float*)d_in[21];
  const float* a_tgt2 = (const float*)d_in[22];
  const float* Wtp2   = (const float*)d_in[23];
  const float* a_tp2  = (const float*)d_in[24];
  const float* b2     = (const float*)d_in[25];
  const float* ln2_g  = (const float*)d_in[26];
  const float* ln2_b  = (const float*)d_in[27];

  // ---- workspace layout (~103 MB) ----
  char* ws = (char*)d_ws;
  size_t off = 0;
  auto alloc = [&](size_t bytes)->char*{
    char* p = ws + off; off = (off + bytes + 255) & ~(size_t)255; return p;
  };
  short* Pb        = (short*)alloc((size_t)N*256*2);   // proj, bf16 (per layer)
  short* hXb       = (short*)alloc((size_t)N*256*2);   // bf16 h: L0 out, then L1 out
  short* Skb       = (short*)alloc((size_t)N*256*2);   // skip GEMM out (L0/L1), then final h
  short* nfb       = (short*)alloc((size_t)N*128*2);   // bf16 node features
  float* s_src     = (float*)alloc((size_t)N*16*4);
  float* s_tgt     = (float*)alloc((size_t)N*16*4);
  float* cvec      = (float*)alloc(256);
  int*   counts    = (int*)alloc((size_t)N*4);
  int*   row_start = (int*)alloc((size_t)(N+1)*4);
  int*   partials  = (int*)alloc(256*4);
  int2*  es        = (int2*)alloc((size_t)E*8);        // packed (src, tp bits), tgt-sorted
  short* W0t       = (short*)alloc((size_t)128*256*2);
  short* Ws0t      = (short*)alloc((size_t)128*256*2);
  short* W1t       = (short*)alloc((size_t)256*256*2);
  short* Ws1t      = (short*)alloc((size_t)256*256*2);
  short* W2t       = (short*)alloc((size_t)256*256*2);
  (void)ws_size; (void)n_in; (void)out_size;

  const int* src = ei;
  const int* tgt = ei + E;

  // ---- prep: weight transposes + nf convert + cvecs ----
  k_wt<<<(256*128+255)/256, 256, 0, stream>>>(W0,     W0t,  128);
  k_wt<<<(256*128+255)/256, 256, 0, stream>>>(Wskip0, Ws0t, 128);
  k_wt<<<(256*256+255)/256, 256, 0, stream>>>(W1,     W1t,  256);
  k_wt<<<(256*256+255)/256, 256, 0, stream>>>(Wskip1, Ws1t, 256);
  k_wt<<<(256*256+255)/256, 256, 0, stream>>>(W2,     W2t,  256);
  k_cvt<<<((N*128/4)+255)/256, 256, 0, stream>>>(nf, nfb, N*128/4);
  k_cvec3<<<3, 256, 0, stream>>>(Wtp0, a_tp0, Wtp1, a_tp1, Wtp2, a_tp2, cvec);

  // ---- CSR build ----
  k_zero<<<(N+255)/256, 256, 0, stream>>>(counts, N);
  k_hist<<<(E+255)/256, 256, 0, stream>>>(tgt, counts, E);
  int NB = (N + 1023) / 1024;
  k_scan1<<<NB, 1024, 0, stream>>>(counts, row_start, partials, N);
  k_scan2<<<1, 64, 0, stream>>>(partials, NB);
  k_scan3<<<(N+255)/256, 256, 0, stream>>>(row_start, partials, counts, N, E);
  k_scatter<<<(E+255)/256, 256, 0, stream>>>(src, tgt, eprob, counts, es, E);

  const int gt = (N + 63) / 64;   // GEMM m-tiles
  const int at = (N + 3) / 4;     // attn blocks (4 waves each)

  // ---- Layer 0: GAT(128 -> 16x16 concat), skip = nf @ Wskip0, ELU, no LN ----
  k_gemm_lds<4,1><<<gt, 256, 0, stream>>>(nfb, W0t, Ws0t, Pb, Skb,
                                          a_src0, a_tgt0, s_src, s_tgt, N);
  k_attn16<0><<<at, 256, 0, stream>>>(row_start, es, s_src, s_tgt, cvec + 0,
                                      Pb, Skb, b0, nullptr, nullptr, hXb, N);

  // ---- Layer 1: GAT(256 -> 16x16 concat), skip = h @ Wskip1, ELU, LN ----
  k_gemm_lds<8,1><<<gt, 256, 0, stream>>>(hXb, W1t, Ws1t, Pb, Skb,
                                          a_src1, a_tgt1, s_src, s_tgt, N);
  k_attn16<1><<<at, 256, 0, stream>>>(row_start, es, s_src, s_tgt, cvec + 16,
                                      Pb, Skb, b1, ln1_g, ln1_b, hXb, N);

  // ---- Layer 2: GAT(256 -> 1x256, avg = identity), identity skip, ELU, LN ----
  k_gemm_lds<8,0><<<gt, 256, 0, stream>>>(hXb, W2t, nullptr, Pb, nullptr,
                                          nullptr, nullptr, nullptr, nullptr, N);
  k_svec1<<<at, 256, 0, stream>>>(Pb, a_src2, a_tgt2, s_src, s_tgt, N);
  k_attn1<<<at, 256, 0, stream>>>(row_start, es, s_src, s_tgt, cvec + 32,
                                  Pb, hXb, b2, ln2_g, ln2_b, Skb, N);

  // ---- gather rows into output (fp32) ----
  k_gather<<<R, 256, 0, stream>>>(Skb, xidx, (float*)d_out, R);
}